// Round 20
// baseline (50.342 us; speedup 1.0000x reference)
//
#include <hip/hip_runtime.h>

#define NB 32
#define TT 512
#define SS 5
#define CC 512
#define UU 256
#define NEGV -1e30f
#define LCH 4                  // timesteps per chunk
#define NCH (TT / LCH)         // 128 chunks
#define PKW 12                 // packed row width: e0..e3, b0..b4, dsh, pad
#define SCANB (2 * NB)         // 64 scan blocks: one per (n, sem)
#define LOG2E 1.4426950408889634f
#define LN2   0.6931471805599453f

// ---------------------------------------------------------------------------
// Kernel A: per-row sum-exp over C=512 (no-max LSE). At HBM roofline
// (27.6 us; 97% of achievable). Base-2 log domain output. Zeroes cnt.
// ---------------------------------------------------------------------------
__global__ __launch_bounds__(512) void row_lse_kernel(
    const float* __restrict__ logits,   // [N][T][S][C]
    const int*   __restrict__ ranges,   // [N][T][S]
    const int*   __restrict__ y,        // [N][U]
    float*       __restrict__ packed,   // [N][T][PKW]
    int*         __restrict__ cnt)      // scan completion counter
{
    if (blockIdx.x == 0 && threadIdx.x == 0) *cnt = 0;

    const int lane = threadIdx.x & 63;
    const int row  = blockIdx.x * 8 + (threadIdx.x >> 6);  // 0..81919
    const float* rowp = logits + (size_t)row * CC;

    float4 a = *(const float4*)(rowp + lane * 4);          // floats [0,256)
    float4 b = *(const float4*)(rowp + 256 + lane * 4);    // floats [256,512)

    float s = __expf(a.x) + __expf(a.y) + __expf(a.z) + __expf(a.w)
            + __expf(b.x) + __expf(b.y) + __expf(b.z) + __expf(b.w);
#pragma unroll
    for (int off = 32; off; off >>= 1)
        s += __shfl_xor(s, off);

    const int   rg    = ranges[row];
    const int   n     = row / (TT * SS);
    const int   sy    = y[n * UU + rg];
    const float emraw = rowp[sy];
    const float blraw = rowp[0];
    const float lse   = __logf(s);

    if (lane == 0) {
        int loc  = row - n * (TT * SS);
        int t    = loc / SS;
        int sidx = loc - t * SS;
        float* dst = packed + ((size_t)n * TT + t) * PKW;
        if (sidx < 4) dst[sidx] = (emraw - lse) * LOG2E;
        dst[4 + sidx] = (blraw - lse) * LOG2E;
        if (sidx == 0) {                       // rg == lb(t) for this row
            float sh = 0.0f;
            if (t < TT - 1)
                sh = (ranges[(n * TT + t + 1) * SS] != rg) ? 1.0f : 0.0f;
            dst[9] = sh;
        }
    }
}

// ---------------------------------------------------------------------------
// Semiring helpers — base-2 log domain (v_exp/v_log ARE base-2: no muls).
// ---------------------------------------------------------------------------
template <bool MAXSEM>
__device__ __forceinline__ float combf(float x, float y) {
    float m = fmaxf(x, y);
    if (MAXSEM) return m;
    return m + __log2f(1.0f + exp2f(-fabsf(x - y)));
}
template <bool MAXSEM>
__device__ __forceinline__ float fold5(float t0, float t1, float t2,
                                       float t3, float t4) {
    float c01 = combf<MAXSEM>(t0, t1);
    float c23 = combf<MAXSEM>(t2, t3);
    return combf<MAXSEM>(combf<MAXSEM>(c01, c23), t4);
}

// composition of one matrix-pair entry (col-major m[j*5+s])
template <bool MAXSEM>
__device__ __forceinline__ float comp_entry(
    const float* __restrict__ A, const float* __restrict__ B, int e)
{
    int jj = e / 5, s = e - jj * 5;
    float t0 = B[s]      + A[jj * 5 + 0];
    float t1 = B[5 + s]  + A[jj * 5 + 1];
    float t2 = B[10 + s] + A[jj * 5 + 2];
    float t3 = B[15 + s] + A[jj * 5 + 3];
    float t4 = B[20 + s] + A[jj * 5 + 4];
    return fold5<MAXSEM>(t0, t1, t2, t3, t4);
}

// ---------------------------------------------------------------------------
// Kernel B: scan + final reduce. 64 blocks x 640 threads.
// Chain (depth 16) from registers; tree 128->16 with 3 barriers; tail
// 16->1 by wave 0 with NO barriers (same-wave DS ops are in program order);
// last-finishing block reduces the 64 partials (r14-proven protocol).
// ---------------------------------------------------------------------------
template <bool MAXSEM>
__device__ __forceinline__ void scan_body(
    const float* __restrict__ packed, float* __restrict__ matA,
    float* __restrict__ matB, float* __restrict__ partials,
    int n, int bid, int tid)
{
    const int c = tid & 127;            // chunk 0..127
    const int j = tid >> 7;             // basis column 0..4

    // ---- register prefetch: 4 timesteps x 3 float4 ----
    const float4* gb = (const float4*)(packed + ((size_t)n * TT + c * LCH) * PKW);
    float4 q0 = gb[0],  q1 = gb[1],  q2 = gb[2];
    float4 q3 = gb[3],  q4 = gb[4],  q5 = gb[5];
    float4 q6 = gb[6],  q7 = gb[7],  q8 = gb[8];
    float4 q9 = gb[9],  q10 = gb[10], q11 = gb[11];

    float v0 = (j == 0) ? 0.0f : NEGV;
    float v1 = (j == 1) ? 0.0f : NEGV;
    float v2 = (j == 2) ? 0.0f : NEGV;
    float v3 = (j == 3) ? 0.0f : NEGV;
    float v4 = (j == 4) ? 0.0f : NEGV;

#define STEP(eA, bA, cA, ti)                                            \
    {                                                                   \
        v1 = combf<MAXSEM>(v1, v0 + eA.x);                              \
        v2 = combf<MAXSEM>(v2, v1 + eA.y);                              \
        v3 = combf<MAXSEM>(v3, v2 + eA.z);                              \
        v4 = combf<MAXSEM>(v4, v3 + eA.w);                              \
        if (c * LCH + ti < TT - 1) {                                    \
            bool sh = cA.y != 0.0f;        /* slot 9 = dsh */           \
            float n0 = sh ? v1 + bA.y : v0 + bA.x;                      \
            float n1 = sh ? v2 + bA.z : v1 + bA.y;                      \
            float n2 = sh ? v3 + bA.w : v2 + bA.z;                      \
            float n3 = sh ? v4 + cA.x : v3 + bA.w;                      \
            float n4 = sh ? NEGV      : v4 + cA.x;                      \
            v0 = n0; v1 = n1; v2 = n2; v3 = n3; v4 = n4;                \
        }                                                               \
    }
    STEP(q0, q1, q2, 0)
    STEP(q3, q4, q5, 1)
    STEP(q6, q7, q8, 2)
    STEP(q9, q10, q11, 3)
#undef STEP

    {
        float* outp = matA + c * 25 + j * 5;     // col-major m[j*5+s]
        outp[0] = v0; outp[1] = v1; outp[2] = v2; outp[3] = v3; outp[4] = v4;
    }
    __syncthreads();

    // ---- tree 128 -> 16: three barriered levels ----
    float* src = matA;
    float* dst = matB;
    int m = NCH;
    while (m > 16) {
        int pairs = m >> 1;
        for (int item = tid; item < pairs * 25; item += 640) {
            int p = item / 25, e = item - p * 25;
            dst[item] = comp_entry<MAXSEM>(src + 2 * p * 25,
                                           src + (2 * p + 1) * 25, e);
        }
        __syncthreads();
        float* tmp = src; src = dst; dst = tmp;
        m = pairs;
    }

    // ---- tail 16 -> 1: wave 0 only, no barriers (same-wave DS in order) ----
    if (tid < 64) {
        while (m > 1) {
            int pairs = m >> 1;
            for (int item = tid; item < pairs * 25; item += 64) {
                int p = item / 25, e = item - p * 25;
                dst[item] = comp_entry<MAXSEM>(src + 2 * p * 25,
                                               src + (2 * p + 1) * 25, e);
            }
            float* tmp = src; src = dst; dst = tmp;
            m = pairs;
        }
        // v_init = e0 -> answer = -M_tot[4][0] = -src[4]  (base-2 domain)
        if (tid == 0) partials[bid] = -src[4];
    }
}

__global__ __launch_bounds__(640) void scan_all(
    const float* __restrict__ packed,   // [N][T][PKW]
    float*       __restrict__ partials, // [SCANB]
    int*         __restrict__ cnt,
    float*       __restrict__ out)      // [2]
{
    __shared__ float matA[NCH * 25];            // 12.8 KB
    __shared__ float matB[(NCH / 2) * 25];      // 6.4 KB
    __shared__ int   amLast;

    const int tid = threadIdx.x;
    const int bid = blockIdx.x;                 // 0..63
    const int n   = bid & 31;
    const int sem = bid >> 5;                   // 0 = lse, 1 = max

    if (sem == 0) scan_body<false>(packed, matA, matB, partials, n, bid, tid);
    else          scan_body<true >(packed, matA, matB, partials, n, bid, tid);

    // ---- completion: last finishing block reduces partials -> out ----
    __syncthreads();                 // partials[bid] written by wave 0
    __threadfence();                 // release
    if (tid == 0) {
        int old = __hip_atomic_fetch_add(cnt, 1, __ATOMIC_ACQ_REL,
                                         __HIP_MEMORY_SCOPE_AGENT);
        amLast = (old == SCANB - 1);
    }
    __syncthreads();
    if (!amLast) return;
    __threadfence();                 // reader-side acquire

    if (tid < 64) {
        float v = partials[tid];     // lanes 0-31: lse, 32-63: max
#pragma unroll
        for (int off = 16; off; off >>= 1)
            v += __shfl_xor(v, off);
        if ((tid & 31) == 0)
            out[tid >> 5] = v * LN2; // out[0]=pruned, out[1]=one_best
    }
}

extern "C" void kernel_launch(void* const* d_in, const int* in_sizes, int n_in,
                              void* d_out, int out_size, void* d_ws, size_t ws_size,
                              hipStream_t stream) {
    const float* logits = (const float*)d_in[0];
    const int*   ranges = (const int*)d_in[1];
    const int*   y      = (const int*)d_in[2];
    // d_in[3] = x_lens, unused (reference ignores it; all == T)

    float* packed   = (float*)d_ws;                       // NB*TT*PKW floats
    float* partials = packed + (size_t)NB * TT * PKW;     // SCANB floats
    int*   cnt      = (int*)(partials + SCANB);           // 1 int
    float* out      = (float*)d_out;

    int rows = NB * TT * SS;                              // 81920
    hipLaunchKernelGGL(row_lse_kernel, dim3(rows / 8), dim3(512), 0, stream,
                       logits, ranges, y, packed, cnt);
    hipLaunchKernelGGL(scan_all, dim3(SCANB), dim3(640), 0, stream,
                       packed, partials, cnt, out);
}

// Round 21
// 40.193 us; speedup vs baseline: 1.2525x; 1.2525x over previous
//
#include <hip/hip_runtime.h>

#define NB 32
#define TT 512
#define SS 5
#define CC 512
#define UU 256
#define NEGV -1e30f
#define LCH 4                  // timesteps per chunk
#define NCH (TT / LCH)         // 128 chunks
#define PKW 12                 // packed row width: e0..e3, b0..b4, dsh, pad
#define SCANB (2 * NB)         // 64 scan blocks: one per (n, sem)
#define LOG2E 1.4426950408889634f
#define LN2   0.6931471805599453f

// ---------------------------------------------------------------------------
// Kernel A: per-row sum-exp over C=512 (no-max LSE). At HBM roofline
// (27.6 us; 97% of achievable 6.29 TB/s). Base-2 log domain output.
// ---------------------------------------------------------------------------
__global__ __launch_bounds__(512) void row_lse_kernel(
    const float* __restrict__ logits,   // [N][T][S][C]
    const int*   __restrict__ ranges,   // [N][T][S]
    const int*   __restrict__ y,        // [N][U]
    float*       __restrict__ packed)   // [N][T][PKW]
{
    const int lane = threadIdx.x & 63;
    const int row  = blockIdx.x * 8 + (threadIdx.x >> 6);  // 0..81919
    const float* rowp = logits + (size_t)row * CC;

    float4 a = *(const float4*)(rowp + lane * 4);          // floats [0,256)
    float4 b = *(const float4*)(rowp + 256 + lane * 4);    // floats [256,512)

    float s = __expf(a.x) + __expf(a.y) + __expf(a.z) + __expf(a.w)
            + __expf(b.x) + __expf(b.y) + __expf(b.z) + __expf(b.w);
#pragma unroll
    for (int off = 32; off; off >>= 1)
        s += __shfl_xor(s, off);

    const int   rg    = ranges[row];
    const int   n     = row / (TT * SS);
    const int   sy    = y[n * UU + rg];
    const float emraw = rowp[sy];
    const float blraw = rowp[0];
    const float lse   = __logf(s);

    if (lane == 0) {
        int loc  = row - n * (TT * SS);
        int t    = loc / SS;
        int sidx = loc - t * SS;
        float* dst = packed + ((size_t)n * TT + t) * PKW;
        if (sidx < 4) dst[sidx] = (emraw - lse) * LOG2E;
        dst[4 + sidx] = (blraw - lse) * LOG2E;
        if (sidx == 0) {                       // rg == lb(t) for this row
            float sh = 0.0f;
            if (t < TT - 1)
                sh = (ranges[(n * TT + t + 1) * SS] != rg) ? 1.0f : 0.0f;
            dst[9] = sh;
        }
    }
}

// ---------------------------------------------------------------------------
// Semiring helpers — base-2 log domain (v_exp/v_log ARE base-2: no muls).
// ---------------------------------------------------------------------------
template <bool MAXSEM>
__device__ __forceinline__ float combf(float x, float y) {
    float m = fmaxf(x, y);
    if (MAXSEM) return m;
    return m + __log2f(1.0f + exp2f(-fabsf(x - y)));
}
template <bool MAXSEM>
__device__ __forceinline__ float fold5(float t0, float t1, float t2,
                                       float t3, float t4) {
    float c01 = combf<MAXSEM>(t0, t1);
    float c23 = combf<MAXSEM>(t2, t3);
    return combf<MAXSEM>(combf<MAXSEM>(c01, c23), t4);
}

// ---------------------------------------------------------------------------
// Kernel B: scan. 64 blocks x 640 threads; thread = (c = tid&127, j = tid>>7).
// Chain (depth 16) entirely from registers; 7-level tree in LDS; partials out
// via plain stores (no fences/atomics — kernel boundary orders visibility;
// r20 proved an in-kernel __threadfence costs ~10 us here).
// ---------------------------------------------------------------------------
template <bool MAXSEM>
__device__ __forceinline__ void scan_body(
    const float* __restrict__ packed, float* __restrict__ matA,
    float* __restrict__ matB, float* __restrict__ partials,
    int n, int bid, int tid)
{
    const int c = tid & 127;            // chunk 0..127
    const int j = tid >> 7;             // basis column 0..4

    // ---- register prefetch: 4 timesteps x 3 float4 ----
    const float4* gb = (const float4*)(packed + ((size_t)n * TT + c * LCH) * PKW);
    float4 q0 = gb[0],  q1 = gb[1],  q2 = gb[2];
    float4 q3 = gb[3],  q4 = gb[4],  q5 = gb[5];
    float4 q6 = gb[6],  q7 = gb[7],  q8 = gb[8];
    float4 q9 = gb[9],  q10 = gb[10], q11 = gb[11];

    float v0 = (j == 0) ? 0.0f : NEGV;
    float v1 = (j == 1) ? 0.0f : NEGV;
    float v2 = (j == 2) ? 0.0f : NEGV;
    float v3 = (j == 3) ? 0.0f : NEGV;
    float v4 = (j == 4) ? 0.0f : NEGV;

#define STEP(eA, bA, cA, ti)                                            \
    {                                                                   \
        v1 = combf<MAXSEM>(v1, v0 + eA.x);                              \
        v2 = combf<MAXSEM>(v2, v1 + eA.y);                              \
        v3 = combf<MAXSEM>(v3, v2 + eA.z);                              \
        v4 = combf<MAXSEM>(v4, v3 + eA.w);                              \
        if (c * LCH + ti < TT - 1) {                                    \
            bool sh = cA.y != 0.0f;        /* slot 9 = dsh */           \
            float n0 = sh ? v1 + bA.y : v0 + bA.x;                      \
            float n1 = sh ? v2 + bA.z : v1 + bA.y;                      \
            float n2 = sh ? v3 + bA.w : v2 + bA.z;                      \
            float n3 = sh ? v4 + cA.x : v3 + bA.w;                      \
            float n4 = sh ? NEGV      : v4 + cA.x;                      \
            v0 = n0; v1 = n1; v2 = n2; v3 = n3; v4 = n4;                \
        }                                                               \
    }
    STEP(q0, q1, q2, 0)
    STEP(q3, q4, q5, 1)
    STEP(q6, q7, q8, 2)
    STEP(q9, q10, q11, 3)
#undef STEP

    {
        float* outp = matA + c * 25 + j * 5;     // col-major m[j*5+s]
        outp[0] = v0; outp[1] = v1; outp[2] = v2; outp[3] = v3; outp[4] = v4;
    }
    __syncthreads();

    // ---- pairwise composition tree: 128 -> 1 (7 levels) ----
    float* src = matA;
    float* dst = matB;
    int m = NCH;
    while (m > 1) {
        int pairs = m >> 1;
        for (int item = tid; item < pairs * 25; item += 640) {
            int p = item / 25, e = item - p * 25;
            int jj = e / 5, s = e - jj * 5;
            const float* A = src + (2 * p) * 25;       // earlier chunk
            const float* B = src + (2 * p + 1) * 25;   // later chunk
            float t0 = B[s]      + A[jj * 5 + 0];
            float t1 = B[5 + s]  + A[jj * 5 + 1];
            float t2 = B[10 + s] + A[jj * 5 + 2];
            float t3 = B[15 + s] + A[jj * 5 + 3];
            float t4 = B[20 + s] + A[jj * 5 + 4];
            dst[item] = fold5<MAXSEM>(t0, t1, t2, t3, t4);
        }
        __syncthreads();
        float* tmp = src; src = dst; dst = tmp;
        m = pairs;
    }
    // v_init = e0 -> answer = -M_tot[4][0] = -src[4]  (base-2 domain)
    if (tid == 0) partials[bid] = -src[4];
}

__global__ __launch_bounds__(640) void scan_all(
    const float* __restrict__ packed,   // [N][T][PKW]
    float*       __restrict__ partials) // [SCANB]
{
    __shared__ float matA[NCH * 25];            // 12.8 KB
    __shared__ float matB[(NCH / 2) * 25];      // 6.4 KB

    const int bid = blockIdx.x;                 // 0..63
    const int n   = bid & 31;
    const int sem = bid >> 5;                   // 0 = lse, 1 = max

    if (sem == 0) scan_body<false>(packed, matA, matB, partials, n, bid, threadIdx.x);
    else          scan_body<true >(packed, matA, matB, partials, n, bid, threadIdx.x);
}

// ---------------------------------------------------------------------------
// Kernel C: final reduce (64 partials -> 2 outputs, rescale base-2 -> e).
// ---------------------------------------------------------------------------
__global__ __launch_bounds__(64) void reduce_kernel(
    const float* __restrict__ partials, float* __restrict__ out)
{
    int tid = threadIdx.x;
    float v = partials[tid];             // lanes 0-31: lse, 32-63: max
#pragma unroll
    for (int off = 16; off; off >>= 1)
        v += __shfl_xor(v, off);
    if ((tid & 31) == 0)
        out[tid >> 5] = v * LN2;         // out[0]=pruned, out[1]=one_best
}

extern "C" void kernel_launch(void* const* d_in, const int* in_sizes, int n_in,
                              void* d_out, int out_size, void* d_ws, size_t ws_size,
                              hipStream_t stream) {
    const float* logits = (const float*)d_in[0];
    const int*   ranges = (const int*)d_in[1];
    const int*   y      = (const int*)d_in[2];
    // d_in[3] = x_lens, unused (reference ignores it; all == T)

    float* packed   = (float*)d_ws;                       // NB*TT*PKW floats
    float* partials = packed + (size_t)NB * TT * PKW;     // SCANB floats
    float* out      = (float*)d_out;

    int rows = NB * TT * SS;                              // 81920
    hipLaunchKernelGGL(row_lse_kernel, dim3(rows / 8), dim3(512), 0, stream,
                       logits, ranges, y, packed);
    hipLaunchKernelGGL(scan_all, dim3(SCANB), dim3(640), 0, stream,
                       packed, partials);
    hipLaunchKernelGGL(reduce_kernel, dim3(1), dim3(64), 0, stream,
                       partials, out);
}